// Round 1
// baseline (354.613 us; speedup 1.0000x reference)
//
#include <hip/hip_runtime.h>
#include <hip/hip_bf16.h>
#include <cstdint>

// Problem shape (Transducer joint network):
//   enc (4,160,640) fp32, dec (4,80,640) fp32, W1 (1280,640), b1 (640),
//   W2 (640,1024), b2 (1024).  out = (4,160,80,1024) fp32 = 52.4M floats.
#define B_    4
#define T_    160
#define U_    80
#define D_    640      // De = Dd = inner
#define V_    1024
#define BT_   640      // B*T
#define BU_   320      // B*U
#define M_    51200    // B*T*U

typedef __bf16 bf16x8 __attribute__((ext_vector_type(8)));
typedef float floatx4 __attribute__((ext_vector_type(4)));

__device__ __forceinline__ void g2l16(const void* g, void* l) {
    __builtin_amdgcn_global_load_lds((const __attribute__((address_space(1))) void*)g,
                                     (__attribute__((address_space(3))) void*)l,
                                     16, 0, 0);
}

__device__ __forceinline__ float fast_tanh(float x) {
    // tanh(x) = 1 - 2/(exp(2x)+1); exp via v_exp_f32 (exp2), rcp via v_rcp_f32.
    // abs error ~1e-7 — far below bf16 quantization.
    float e = __builtin_amdgcn_exp2f(x * 2.8853900817779268f); // 2*log2(e)
    return 1.0f - 2.0f * __builtin_amdgcn_rcpf(e + 1.0f);
}

// ---------------------------------------------------------------------------
// Kernel 1: fp32 projections. Rows 0..639 = enc @ W1[:640]; rows 640..959
// (as dec rows 0..319) = dec @ W1[640:]. 32x32 C-tiles, BK=32, 256 threads.
// fp32 here keeps pre-tanh error negligible so the whole error budget goes
// to the bf16 main GEMM.
// ---------------------------------------------------------------------------
__global__ __launch_bounds__(256) void proj_kernel(
    const float* __restrict__ enc, const float* __restrict__ dec,
    const float* __restrict__ W1,
    float* __restrict__ encp, float* __restrict__ decp) {
    __shared__ float As[32][36];   // pad 36: keeps 16B alignment, breaks bank clash
    __shared__ float Ws[32][36];

    const int rt = blockIdx.y;     // 0..29 (20 enc row-tiles, 10 dec row-tiles)
    const int ct = blockIdx.x;     // 0..19 (640 cols / 32)
    const float* Asrc;
    const float* Wsrc;
    float* Cdst;
    if (rt < 20) { Asrc = enc + (size_t)rt * 32 * D_;        Wsrc = W1;             Cdst = encp + (size_t)rt * 32 * D_; }
    else         { Asrc = dec + (size_t)(rt - 20) * 32 * D_; Wsrc = W1 + D_ * D_;   Cdst = decp + (size_t)(rt - 20) * 32 * D_; }

    const int tid = threadIdx.x;
    const int ar = tid >> 3, ac = (tid & 7) * 4;  // staging: 4 floats/thread
    const int tr = tid >> 4, tc = tid & 15;       // compute: 2x2 outputs/thread

    float a00 = 0.f, a01 = 0.f, a10 = 0.f, a11 = 0.f;
    for (int k0 = 0; k0 < D_; k0 += 32) {
        __syncthreads();
        *(floatx4*)&As[ar][ac] = *(const floatx4*)&Asrc[(size_t)ar * D_ + k0 + ac];
        *(floatx4*)&Ws[ar][ac] = *(const floatx4*)&Wsrc[(size_t)(k0 + ar) * D_ + ct * 32 + ac];
        __syncthreads();
#pragma unroll
        for (int kk = 0; kk < 32; kk++) {
            float x0 = As[tr * 2][kk], x1 = As[tr * 2 + 1][kk];
            float w0 = Ws[kk][tc * 2], w1 = Ws[kk][tc * 2 + 1];
            a00 += x0 * w0; a01 += x0 * w1;
            a10 += x1 * w0; a11 += x1 * w1;
        }
    }
    const int cc = ct * 32 + tc * 2;
    Cdst[(size_t)(tr * 2) * D_ + cc]     = a00;
    Cdst[(size_t)(tr * 2) * D_ + cc + 1] = a01;
    Cdst[(size_t)(tr * 2 + 1) * D_ + cc]     = a10;
    Cdst[(size_t)(tr * 2 + 1) * D_ + cc + 1] = a11;
}

// ---------------------------------------------------------------------------
// Kernel 2: W2 (640x1024 fp32, KxN) -> W2t (1024x640 bf16, NxK) so MFMA
// B-fragments are contiguous-in-K (ds_read_b128 from LDS).
// ---------------------------------------------------------------------------
__global__ __launch_bounds__(256) void w2t_kernel(
    const float* __restrict__ W2, __bf16* __restrict__ W2t) {
    __shared__ __bf16 tile[32][33];
    const int vt = blockIdx.x;           // 0..31
    const int kt = blockIdx.y;           // 0..19
    const int tx = threadIdx.x & 31, ty = threadIdx.x >> 5;  // 32x8
#pragma unroll
    for (int i = 0; i < 4; i++)
        tile[ty + i * 8][tx] = (__bf16)W2[(size_t)(kt * 32 + ty + i * 8) * V_ + vt * 32 + tx];
    __syncthreads();
#pragma unroll
    for (int i = 0; i < 4; i++)
        W2t[(size_t)(vt * 32 + ty + i * 8) * D_ + kt * 32 + tx] = tile[tx][ty + i * 8];
}

// ---------------------------------------------------------------------------
// Kernel 3: hidden[m][h] = tanh(encp[bt][h] + decp[b*80+u][h] + b1[h]) -> bf16
// m = bt*80 + u. One thread per 8 h-values; fully coalesced 16B stores.
// encp/decp re-reads are L2-served (2.4 MB working set).
// ---------------------------------------------------------------------------
__global__ __launch_bounds__(256) void hidden_kernel(
    const float* __restrict__ encp, const float* __restrict__ decp,
    const float* __restrict__ b1, __bf16* __restrict__ H) {
    const unsigned g = blockIdx.x * 256u + threadIdx.x;  // 0..4,095,999
    const unsigned row = g / 80u;   // m index 0..51199
    const unsigned hg  = g % 80u;   // h-group (8 elems)
    const unsigned u   = row % 80u;
    const unsigned bt  = row / 80u;
    const unsigned b   = bt / 160u;

    const float* ep = encp + (size_t)bt * D_ + hg * 8;
    const float* dp = decp + (size_t)(b * 80u + u) * D_ + hg * 8;
    const float* bp = b1 + hg * 8;

    floatx4 e0 = *(const floatx4*)ep,       e1 = *(const floatx4*)(ep + 4);
    floatx4 d0 = *(const floatx4*)dp,       d1 = *(const floatx4*)(dp + 4);
    floatx4 c0 = *(const floatx4*)bp,       c1 = *(const floatx4*)(bp + 4);

    bf16x8 hv;
#pragma unroll
    for (int i = 0; i < 4; i++) hv[i]     = (__bf16)fast_tanh(e0[i] + d0[i] + c0[i]);
#pragma unroll
    for (int i = 0; i < 4; i++) hv[i + 4] = (__bf16)fast_tanh(e1[i] + d1[i] + c1[i]);

    *(bf16x8*)(H + (size_t)g * 8) = hv;
}

// ---------------------------------------------------------------------------
// Kernel 4: C[51200x1024] = H[51200x640] @ W2t[1024x640]^T + b2, fp32 out.
// m97 structure: 128x128 tile, 4 waves (each 64x64 = 4x4 MFMA tiles),
// BK=32, global_load_lds width=16, ds_read_b128 fragments,
// mfma_f32_16x16x32_bf16, fp32 accum.
// ---------------------------------------------------------------------------
__global__ __launch_bounds__(256) void gemm_kernel(
    const __bf16* __restrict__ H, const __bf16* __restrict__ W2t,
    const float* __restrict__ b2, float* __restrict__ C) {
    __shared__ __bf16 As[128 * 32];
    __shared__ __bf16 Bs[128 * 32];

    const int bx = blockIdx.x;
    const int nt = bx & 7;        // 8 N-tiles — matches XCD round-robin (W2t strip stays in each XCD's L2)
    const int mt = bx >> 3;       // 400 M-tiles
    const int m0 = mt * 128, n0 = nt * 128;

    const int tid = threadIdx.x;
    const int lane = tid & 63;
    const int wave = tid >> 6;
    const int wm = (wave & 1) * 64, wn = (wave >> 1) * 64;
    const int lr = lane & 15, qd = lane >> 4;

    // staging: thread loads 16B; LDS dest = wave-uniform base + lane*16 (required!)
    const int r = tid >> 2;            // 0..63
    const int c = (tid & 3) * 8;       // 0,8,16,24
    const __bf16* Ag = H   + (size_t)(m0 + r) * D_ + c;
    const __bf16* Bg = W2t + (size_t)(n0 + r) * D_ + c;
    __bf16* Al = &As[r * 32 + c];      // byte offset = tid*16
    __bf16* Bl = &Bs[r * 32 + c];

    floatx4 acc[4][4] = {};

    for (int k0 = 0; k0 < D_; k0 += 32) {
        __syncthreads();               // prior tile's readers done
        g2l16(Ag + k0,                 Al);
        g2l16(Ag + k0 + 64 * D_,       Al + 64 * 32);
        g2l16(Bg + k0,                 Bl);
        g2l16(Bg + k0 + 64 * D_,       Bl + 64 * 32);
        __syncthreads();               // drains vmcnt → tile visible

        bf16x8 af[4], wf[4];
#pragma unroll
        for (int i = 0; i < 4; i++)
            af[i] = *(const bf16x8*)&As[(wm + i * 16 + lr) * 32 + qd * 8];
#pragma unroll
        for (int j = 0; j < 4; j++)
            wf[j] = *(const bf16x8*)&Bs[(wn + j * 16 + lr) * 32 + qd * 8];
#pragma unroll
        for (int i = 0; i < 4; i++)
#pragma unroll
            for (int j = 0; j < 4; j++)
                acc[i][j] = __builtin_amdgcn_mfma_f32_16x16x32_bf16(af[i], wf[j], acc[i][j], 0, 0, 0);
    }

    // Epilogue: C/D layout col = lane&15, row = (lane>>4)*4 + reg (m89-verified)
    float bias[4];
#pragma unroll
    for (int j = 0; j < 4; j++) bias[j] = b2[n0 + wn + j * 16 + lr];
#pragma unroll
    for (int i = 0; i < 4; i++) {
#pragma unroll
        for (int j = 0; j < 4; j++) {
            const int col = n0 + wn + j * 16 + lr;
#pragma unroll
            for (int rg = 0; rg < 4; rg++) {
                const int row = m0 + wm + i * 16 + qd * 4 + rg;
                C[(size_t)row * V_ + col] = acc[i][j][rg] + bias[j];
            }
        }
    }
}

// ---------------------------------------------------------------------------
extern "C" void kernel_launch(void* const* d_in, const int* in_sizes, int n_in,
                              void* d_out, int out_size, void* d_ws, size_t ws_size,
                              hipStream_t stream) {
    const float* enc = (const float*)d_in[0];
    const float* dec = (const float*)d_in[1];
    const float* W1  = (const float*)d_in[2];
    const float* b1  = (const float*)d_in[3];
    const float* W2  = (const float*)d_in[4];
    const float* b2  = (const float*)d_in[5];
    float* out = (float*)d_out;

    // Workspace layout (all 16B aligned), total ~69.3 MB:
    char* ws = (char*)d_ws;
    float*  encp = (float*)ws;                                   // 640*640*4   = 1,638,400
    float*  decp = (float*)(ws + 1638400);                       // 320*640*4   =   819,200
    __bf16* W2t  = (__bf16*)(ws + 1638400 + 819200);             // 1024*640*2  = 1,310,720
    __bf16* Hbuf = (__bf16*)(ws + 1638400 + 819200 + 1310720);   // 51200*640*2 = 65,536,000

    proj_kernel<<<dim3(20, 30), 256, 0, stream>>>(enc, dec, W1, encp, decp);
    w2t_kernel<<<dim3(32, 20), 256, 0, stream>>>(W2, W2t);
    hidden_kernel<<<16000, 256, 0, stream>>>(encp, decp, b1, Hbuf);
    gemm_kernel<<<3200, 256, 0, stream>>>(Hbuf, W2t, b2, out);
}